// Round 2
// baseline (99.494 us; speedup 1.0000x reference)
//
#include <hip/hip_runtime.h>
#include <hip/hip_bf16.h>
#include <math.h>

// Chamfer distance via K-packed MFMA, B=8, N=M=8192, D=3, fp32.
//   C[m][n] = q_m.r_n - 0.5*||r_n||^2 via ONE v_mfma_f32_32x32x16_bf16:
//     lanes<32  (k0-7) : A={qh,1, ql,0}  B={rh,wh, rh,wh}
//     lanes>=32 (k8-15): A={qh,1, 0,0}   B={rl,wl, 0,0}
//   (hi/lo bf16 split; dropped ql.rl term ~2^-17 relative)
//   min_j d2 = ||q||^2_fp32 - 2*max_n C, clamped at 0.
// R8: counter calibration (cold dispatch MfmaUtil 2.76 @140us) shows the
// 32x32x16 pipe rate is 8.07 cyc/CU -> MFMA floor = 13.8us; R0's 42us had
// MfmaUtil 32%, VALUBusy 45% (~88 VALU/iter, half of it packing junk).
// Changes to make MFMA the binding pipe:
//   (a) prep pre-expands refs to per-lane B-fragments (32B/pt): lanes<32
//       read {rh,wh,rh,wh}, lanes>=32 read {rl,wl,0,0}. Inner loop is now
//       2x ds_read_b128 + 4 MFMA + 32 v_max3 - zero pack VALU.
//   (b) MFMA acc = inline constant 0 (no zc tuple: -16 VGPR, no init).
//   (c) regs ~118 < 128 and LDS 36864 -> 4 blocks/CU truly resident.
//       SREF=512 (16KiB/buffer, double-buffered, aliased w/ transpose buf).

#define BLOCK 256
#define WAVES 4
#define QPW 64        // queries per wave (two 32-row MFMA groups)
#define NCHUNK 2      // ref-dim split across blockIdx.y
#define SREF 512      // refs per LDS stage
#define STAGE_BYTES (SREF * 32)   // 16 KiB per buffer (32B per ref)
#define IPS (SREF / 64)           // 8 iterations per stage

typedef short short8 __attribute__((ext_vector_type(8)));
typedef float f32x16 __attribute__((ext_vector_type(16)));
typedef unsigned int u32;
typedef __attribute__((address_space(1))) const u32 gu32;
typedef __attribute__((address_space(3))) u32 lu32;

__device__ __forceinline__ unsigned int bf16hi(float f) {
    __hip_bfloat16 h = __float2bfloat16(f);
    return (unsigned int)*reinterpret_cast<unsigned short*>(&h);
}
__device__ __forceinline__ float bf16f(unsigned int u) {
    unsigned short us = (unsigned short)u;
    __hip_bfloat16 h;
    *reinterpret_cast<unsigned short*>(&h) = us;
    return __bfloat162float(h);
}

// acc = inline constant 0: compiler-style zero accumulator, no C tuple.
__device__ __forceinline__ f32x16 mfma_bf16_z(short8 a, short8 b) {
    f32x16 d;
    asm volatile("v_mfma_f32_32x32x16_bf16 %0, %1, %2, 0"
                 : "=&v"(d) : "v"(a), "v"(b));
    return d;
}
// Inline asm bypasses the compiler hazard recognizer: enforce >=16 cycles
// between last MFMA issue and first VALU read of dests; reads ordered
// oldest-first so each dest ages >= the margin validated in R0 (24cy).
__device__ __forceinline__ void mfma_fence4(f32x16& a, f32x16& b, f32x16& c, f32x16& d) {
    asm volatile("s_nop 7\n\ts_nop 7" : "+v"(a), "+v"(b), "+v"(c), "+v"(d));
}

__device__ __forceinline__ void gload_lds16(const void* g, void* l) {
    __builtin_amdgcn_global_load_lds((gu32*)g, (lu32*)l, 16, 0, 0);
}

// Per point:
//   recQ: one 16B record {xh|yh, zh|wh, xl|yl, zl|wl}, w = -0.5*||p||^2
//   recB: pre-expanded B-fragment stream, tile t = points [32t,32t+32),
//         1024B per tile:
//           bytes [t*1024 + m*16]       = {hx,hz, hx,hz}  (hi dup, lanes<32)
//           bytes [t*1024 + 512 + m*16] = {lx,lz, 0, 0}   (lo,     lanes>=32)
//         where hx = xh|(yh<<16) etc. Lane l of a wave reads t*1024 + l*16.
//   q2:   fp32 ||p||^2 (exact) for the reduce pass.
__global__ void prep_kernel(const float* __restrict__ gts, const float* __restrict__ preds,
                            int nG, int nP, uint4* __restrict__ recQ,
                            unsigned char* __restrict__ recB, float* __restrict__ q2,
                            float* out) {
    const int idx = blockIdx.x * blockDim.x + threadIdx.x;
    if (idx == 0) out[0] = 0.0f;
    if (idx >= nG + nP) return;
    const float* src;
    unsigned char* rb;
    if (idx < nG) {
        src = gts + 3 * (size_t)idx;
        rb  = recB + (size_t)(idx >> 5) * 1024 + (size_t)(idx & 31) * 16;
    } else {
        const int j = idx - nG;
        src = preds + 3 * (size_t)j;
        rb  = recB + (size_t)nG * 32 + (size_t)(j >> 5) * 1024 + (size_t)(j & 31) * 16;
    }
    const float x = src[0], y = src[1], z = src[2];
    const float n2 = x * x + y * y + z * z;
    const float w = -0.5f * n2;
    q2[idx] = n2;
    const unsigned int xh = bf16hi(x), yh = bf16hi(y), zh = bf16hi(z), wh = bf16hi(w);
    const unsigned int xl = bf16hi(x - bf16f(xh));
    const unsigned int yl = bf16hi(y - bf16f(yh));
    const unsigned int zl = bf16hi(z - bf16f(zh));
    const unsigned int wl = bf16hi(w - bf16f(wh));
    const unsigned int hx = xh | (yh << 16), hz = zh | (wh << 16);
    const unsigned int lx = xl | (yl << 16), lz = zl | (wl << 16);
    recQ[idx] = make_uint4(hx, hz, lx, lz);
    *(uint4*)(rb)       = make_uint4(hx, hz, hx, hz);
    *(uint4*)(rb + 512) = make_uint4(lx, lz, 0u, 0u);
}

// kpart layout: float kpart[NCHUNK][nG + nP]; slot = blockIdx.y.
__global__ void __launch_bounds__(BLOCK, 4)
nn_kernel(const uint4* __restrict__ recQ, const unsigned char* __restrict__ recB,
          float* __restrict__ kpart, int N, int M, int B) {
    const int z = blockIdx.z;
    const bool dirX = (z < B);
    const int b = dirX ? z : z - B;
    const int NQ = dirX ? N : M;
    const int NR = dirX ? M : N;
    const uint4* Qr = recQ + (dirX ? 0 : (size_t)B * N) + (size_t)b * NQ;
    const int chunk = NR / NCHUNK;
    const unsigned char* Rb = recB + (dirX ? (size_t)B * N * 32 : 0)
                              + ((size_t)b * NR + (size_t)blockIdx.y * chunk) * 32;
    const int nGP = B * (N + M);
    float* outK = kpart + (size_t)blockIdx.y * nGP + (dirX ? 0 : B * N) + (size_t)b * NQ;

    const int tid = threadIdx.x;
    const int lane = tid & 63;
    const int wave = tid >> 6;
    const int m = lane & 31;
    const unsigned int loMask = (lane >= 32) ? 0u : 0xFFFFFFFFu;
    const int qBase = (blockIdx.x * WAVES + wave) * QPW;

    // ---- A fragments (two 32-row groups)
    const uint4 q0 = Qr[qBase + m];
    const uint4 q1 = Qr[qBase + 32 + m];
    union { uint4 v; short8 s; } a;
    a.v.x = q0.x;                                   // (qxh, qyh)
    a.v.y = (q0.y & 0xFFFFu) | 0x3F800000u;         // (qzh, 1.0bf16)
    a.v.z = q0.z & loMask;                          // (qxl, qyl) | 0
    a.v.w = q0.w & 0xFFFFu & loMask;                // (qzl, 0)   | 0
    const short8 A0 = a.s;
    a.v.x = q1.x;
    a.v.y = (q1.y & 0xFFFFu) | 0x3F800000u;
    a.v.z = q1.z & loMask;
    a.v.w = q1.w & 0xFFFFu & loMask;
    const short8 A1 = a.s;

    f32x16 k0, k1;
    #pragma unroll
    for (int r = 0; r < 16; ++r) { k0[r] = -INFINITY; k1[r] = -INFINITY; }

    // Staging buffers (2 x 16 KiB) alias the epilogue transpose buffer.
    __shared__ __align__(16) unsigned char smem[WAVES * 64 * 36 * 4];  // 36864 B

    // Each wave stages its 4 KiB slice: 4 x global_load_lds of 1 KiB
    // (64 lanes x 16B, linear dest = wave-uniform base + lane*16).
    const unsigned char* gsrc = Rb + (size_t)wave * 4096 + (size_t)lane * 16;
    unsigned char* lbase = smem + wave * 4096;
    auto stage_issue = [&](int s) {
        const unsigned char* g = gsrc + (size_t)s * STAGE_BYTES;
        unsigned char* l = lbase + ((s & 1) * STAGE_BYTES);
        #pragma unroll
        for (int k2 = 0; k2 < 4; ++k2)
            gload_lds16(g + k2 * 1024, l + k2 * 1024);
    };

    const int nStages = chunk / SREF;               // 8
    stage_issue(0);
    __syncthreads();                                // drains vmcnt(0)

    #pragma unroll 1
    for (int s = 0; s < nStages; ++s) {
        if (s + 1 < nStages) stage_issue(s + 1);    // fills other buffer
        // Lane l reads its pre-expanded 16B fragment of tiles 2i, 2i+1.
        const unsigned char* tb = smem + ((s & 1) * STAGE_BYTES) + lane * 16;
        #pragma unroll
        for (int i = 0; i < IPS; ++i) {
            const short8 b0 = *(const short8*)(tb + i * 2048);
            const short8 b1 = *(const short8*)(tb + i * 2048 + 1024);

            f32x16 c0 = mfma_bf16_z(A0, b0);
            f32x16 c1 = mfma_bf16_z(A0, b1);
            f32x16 c2 = mfma_bf16_z(A1, b0);
            f32x16 c3 = mfma_bf16_z(A1, b1);
            mfma_fence4(c0, c1, c2, c3);
            #pragma unroll
            for (int r = 0; r < 16; ++r)
                k0[r] = fmaxf(fmaxf(c0[r], c1[r]), k0[r]);   // v_max3
            #pragma unroll
            for (int r = 0; r < 16; ++r)
                k1[r] = fmaxf(fmaxf(c2[r], c3[r]), k1[r]);
        }
        __syncthreads();   // drains vmcnt(0): next buffer published
    }

    // ---- epilogue: LDS transpose, then each lane max-reduces one query row.
    // C/D layout: col=lane&31, row=(r&3)+8*(r>>2)+4*(lane>>5).
    float (*sT)[64][36] = (float (*)[64][36])smem;  // +4 pad: conflict-free
    #pragma unroll
    for (int r = 0; r < 16; ++r) {
        const int row = (r & 3) + 8 * (r >> 2) + 4 * (lane >> 5);
        sT[wave][row][m]      = k0[r];              // group 0 -> rows 0..31
        sT[wave][32 + row][m] = k1[r];              // group 1 -> rows 32..63
    }
    // wave-private region; compiler inserts the lgkmcnt waits.
    const float4* rowp = (const float4*)&sT[wave][lane][0];
    float4 m01 = rowp[0];
    #pragma unroll
    for (int kk = 1; kk < 8; ++kk) {
        const float4 t = rowp[kk];
        m01.x = fmaxf(m01.x, t.x); m01.y = fmaxf(m01.y, t.y);
        m01.z = fmaxf(m01.z, t.z); m01.w = fmaxf(m01.w, t.w);
    }
    const float cmax = fmaxf(fmaxf(m01.x, m01.y), fmaxf(m01.z, m01.w));
    outK[qBase + lane] = cmax;                      // coalesced, no atomics
}

// d2 = max(0, ||q||^2 - 2*max(kpart[0], kpart[1])); weighted means, one
// atomicAdd per block. q2 precomputed fp32 in prep.
__global__ void __launch_bounds__(BLOCK)
reduce_kernel(const float* __restrict__ kpart, const float* __restrict__ q2,
              int nG, int nP, float invx, float invy, float* __restrict__ out) {
    const int total = nG + nP;
    float local = 0.0f;
    for (int idx = blockIdx.x * blockDim.x + threadIdx.x; idx < total;
         idx += gridDim.x * blockDim.x) {
        const float c = fmaxf(kpart[idx], kpart[total + idx]);
        const float inv = (idx < nG) ? invx : invy;
        local += fmaxf(q2[idx] - 2.0f * c, 0.0f) * inv;
    }
    __shared__ float waveSums[BLOCK / 64];
    float v = local;
    #pragma unroll
    for (int off = 32; off; off >>= 1) v += __shfl_xor(v, off);
    if ((threadIdx.x & 63) == 0) waveSums[threadIdx.x >> 6] = v;
    __syncthreads();
    if (threadIdx.x == 0) {
        float s = 0.0f;
        #pragma unroll
        for (int w = 0; w < BLOCK / 64; ++w) s += waveSums[w];
        atomicAdd(out, s);
    }
}

extern "C" void kernel_launch(void* const* d_in, const int* in_sizes, int n_in,
                              void* d_out, int out_size, void* d_ws, size_t ws_size,
                              hipStream_t stream) {
    const float* gts   = (const float*)d_in[0];   // [B, N, 3]
    const float* preds = (const float*)d_in[1];   // [B, M, 3]
    float* out = (float*)d_out;

    const int B = 8;
    const int N = in_sizes[0] / (B * 3);
    const int M = in_sizes[1] / (B * 3);
    const int nG = B * N, nP = B * M;

    uint4* recQ = (uint4*)d_ws;                                // (nG+nP)*16B (2 MB)
    unsigned char* recB = (unsigned char*)(recQ + nG + nP);    // (nG+nP)*32B (4 MB)
    float* kpart = (float*)(recB + (size_t)(nG + nP) * 32);    // NCHUNK*(nG+nP) (1 MB)
    float* q2    = kpart + (size_t)NCHUNK * (nG + nP);         // (nG+nP) (0.5 MB)

    prep_kernel<<<(nG + nP + BLOCK - 1) / BLOCK, BLOCK, 0, stream>>>(
        gts, preds, nG, nP, recQ, recB, q2, out);

    dim3 grid(N / (WAVES * QPW), NCHUNK, 2 * B);  // 32 x 2 x 16 = 1024 = 4/CU
    nn_kernel<<<grid, BLOCK, 0, stream>>>(recQ, recB, kpart, N, M, B);

    reduce_kernel<<<256, BLOCK, 0, stream>>>(
        kpart, q2, nG, nP, 1.0f / (float)nG, 1.0f / (float)nP, out);
}

// Round 4
// 98.166 us; speedup vs baseline: 1.0135x; 1.0135x over previous
//
#include <hip/hip_runtime.h>
#include <hip/hip_bf16.h>
#include <math.h>

// Chamfer distance via K-packed MFMA, B=8, N=M=8192, D=3, fp32.
//   C[m][n] = q_m.r_n - 0.5*||r_n||^2 via ONE v_mfma_f32_32x32x16_bf16:
//     lanes<32  (k0-7) : A={qh,1, ql,0}  B={rh,wh, rh,wh}
//     lanes>=32 (k8-15): A={qh,1, 0,0}   B={rl,wl, 0,0}
//   (hi/lo bf16 split; dropped ql.rl term ~2^-17 relative)
//   min_j d2 = ||q||^2_fp32 - 2*max_n C, clamped at 0.
// R10: R9's fence-free 2-deep pipeline FAILED numerics (absmax 2x thresh):
// asm volatile is not a scheduling barrier for plain VALU, so LLVM could
// cluster both issue groups then both folds, putting the first v_max3 read
// of a dest ~4-8 cyc after its MFMA issue (<26cy hazard window; inline asm
// bypasses the hazard recognizer -> stale reads, small error). Fix per
// rule #18: sched_barrier(0) pinned after each 4-MFMA issue group (pinned
// read-age >= other-set fold = 64+ cyc) + light data-tied s_nop 7 fence
// (8 cyc insurance) on the set about to be folded. Pipeline retained:
//   - iter i issues set A while folding set B issued at i-1
//   - b operands prefetched 1 iter ahead (LDS latency off critical path)
//   - __launch_bounds__(256,2): ~210 regs, waves stall only on MFMA
//     backpressure -> MFMA pipe becomes the binding resource (13.8us floor).

#define BLOCK 256
#define WAVES 4
#define QPW 64        // queries per wave (two 32-row MFMA groups)
#define NCHUNK 2      // ref-dim split across blockIdx.y
#define SREF 512      // refs per LDS stage
#define STAGE_BYTES (SREF * 32)   // 16 KiB per buffer (32B per ref)
#define IPS (SREF / 64)           // 8 iterations per stage

typedef short short8 __attribute__((ext_vector_type(8)));
typedef float f32x16 __attribute__((ext_vector_type(16)));
typedef unsigned int u32;
typedef __attribute__((address_space(1))) const u32 gu32;
typedef __attribute__((address_space(3))) u32 lu32;

#define SB() __builtin_amdgcn_sched_barrier(0)

__device__ __forceinline__ unsigned int bf16hi(float f) {
    __hip_bfloat16 h = __float2bfloat16(f);
    return (unsigned int)*reinterpret_cast<unsigned short*>(&h);
}
__device__ __forceinline__ float bf16f(unsigned int u) {
    unsigned short us = (unsigned short)u;
    __hip_bfloat16 h;
    *reinterpret_cast<unsigned short*>(&h) = us;
    return __bfloat162float(h);
}

// acc = inline constant 0; earlyclobber so dest never aliases live srcs.
__device__ __forceinline__ f32x16 mfma_bf16_z(short8 a, short8 b) {
    f32x16 d;
    asm volatile("v_mfma_f32_32x32x16_bf16 %0, %1, %2, 0"
                 : "=&v"(d) : "v"(a), "v"(b));
    return d;
}

// Data-tied hazard margin on the set about to be folded (reads ordered
// oldest-first in fold4). Combined with the SB() pins this gives every
// MFMA dest >= ~80 cyc of age before its first VALU read.
__device__ __forceinline__ void mfma_fence4(f32x16& a, f32x16& b, f32x16& c, f32x16& d) {
    asm volatile("s_nop 7" : "+v"(a), "+v"(b), "+v"(c), "+v"(d));
}

__device__ __forceinline__ void gload_lds16(const void* g, void* l) {
    __builtin_amdgcn_global_load_lds((gu32*)g, (lu32*)l, 16, 0, 0);
}

// Fold one 4-tuple set into the running maxima (32 v_max3).
__device__ __forceinline__ void fold4(const f32x16& x, const f32x16& y,
                                      const f32x16& z, const f32x16& w,
                                      f32x16& k0, f32x16& k1) {
    #pragma unroll
    for (int r = 0; r < 16; ++r) k0[r] = fmaxf(fmaxf(x[r], y[r]), k0[r]);
    #pragma unroll
    for (int r = 0; r < 16; ++r) k1[r] = fmaxf(fmaxf(z[r], w[r]), k1[r]);
}

// Per point:
//   recQ: one 16B record {xh|yh, zh|wh, xl|yl, zl|wl}, w = -0.5*||p||^2
//   recB: pre-expanded B-fragment stream, tile t = points [32t,32t+32),
//         1024B per tile:
//           bytes [t*1024 + m*16]       = {hx,hz, hx,hz}  (hi dup, lanes<32)
//           bytes [t*1024 + 512 + m*16] = {lx,lz, 0, 0}   (lo,     lanes>=32)
//   q2:   fp32 ||p||^2 (exact) for the reduce pass.
__global__ void prep_kernel(const float* __restrict__ gts, const float* __restrict__ preds,
                            int nG, int nP, uint4* __restrict__ recQ,
                            unsigned char* __restrict__ recB, float* __restrict__ q2,
                            float* out) {
    const int idx = blockIdx.x * blockDim.x + threadIdx.x;
    if (idx == 0) out[0] = 0.0f;
    if (idx >= nG + nP) return;
    const float* src;
    unsigned char* rb;
    if (idx < nG) {
        src = gts + 3 * (size_t)idx;
        rb  = recB + (size_t)(idx >> 5) * 1024 + (size_t)(idx & 31) * 16;
    } else {
        const int j = idx - nG;
        src = preds + 3 * (size_t)j;
        rb  = recB + (size_t)nG * 32 + (size_t)(j >> 5) * 1024 + (size_t)(j & 31) * 16;
    }
    const float x = src[0], y = src[1], z = src[2];
    const float n2 = x * x + y * y + z * z;
    const float w = -0.5f * n2;
    q2[idx] = n2;
    const unsigned int xh = bf16hi(x), yh = bf16hi(y), zh = bf16hi(z), wh = bf16hi(w);
    const unsigned int xl = bf16hi(x - bf16f(xh));
    const unsigned int yl = bf16hi(y - bf16f(yh));
    const unsigned int zl = bf16hi(z - bf16f(zh));
    const unsigned int wl = bf16hi(w - bf16f(wh));
    const unsigned int hx = xh | (yh << 16), hz = zh | (wh << 16);
    const unsigned int lx = xl | (yl << 16), lz = zl | (wl << 16);
    recQ[idx] = make_uint4(hx, hz, lx, lz);
    *(uint4*)(rb)       = make_uint4(hx, hz, hx, hz);
    *(uint4*)(rb + 512) = make_uint4(lx, lz, 0u, 0u);
}

// kpart layout: float kpart[NCHUNK][nG + nP]; slot = blockIdx.y.
__global__ void __launch_bounds__(BLOCK, 2)
nn_kernel(const uint4* __restrict__ recQ, const unsigned char* __restrict__ recB,
          float* __restrict__ kpart, int N, int M, int B) {
    const int z = blockIdx.z;
    const bool dirX = (z < B);
    const int b = dirX ? z : z - B;
    const int NQ = dirX ? N : M;
    const int NR = dirX ? M : N;
    const uint4* Qr = recQ + (dirX ? 0 : (size_t)B * N) + (size_t)b * NQ;
    const int chunk = NR / NCHUNK;
    const unsigned char* Rb = recB + (dirX ? (size_t)B * N * 32 : 0)
                              + ((size_t)b * NR + (size_t)blockIdx.y * chunk) * 32;
    const int nGP = B * (N + M);
    float* outK = kpart + (size_t)blockIdx.y * nGP + (dirX ? 0 : B * N) + (size_t)b * NQ;

    const int tid = threadIdx.x;
    const int lane = tid & 63;
    const int wave = tid >> 6;
    const int m = lane & 31;
    const unsigned int loMask = (lane >= 32) ? 0u : 0xFFFFFFFFu;
    const int qBase = (blockIdx.x * WAVES + wave) * QPW;

    // ---- A fragments (two 32-row groups)
    const uint4 q0 = Qr[qBase + m];
    const uint4 q1 = Qr[qBase + 32 + m];
    union { uint4 v; short8 s; } a;
    a.v.x = q0.x;                                   // (qxh, qyh)
    a.v.y = (q0.y & 0xFFFFu) | 0x3F800000u;         // (qzh, 1.0bf16)
    a.v.z = q0.z & loMask;                          // (qxl, qyl) | 0
    a.v.w = q0.w & 0xFFFFu & loMask;                // (qzl, 0)   | 0
    const short8 A0 = a.s;
    a.v.x = q1.x;
    a.v.y = (q1.y & 0xFFFFu) | 0x3F800000u;
    a.v.z = q1.z & loMask;
    a.v.w = q1.w & 0xFFFFu & loMask;
    const short8 A1 = a.s;

    f32x16 k0, k1;
    #pragma unroll
    for (int r = 0; r < 16; ++r) { k0[r] = -INFINITY; k1[r] = -INFINITY; }

    // 2-deep MFMA pipeline sets. cB acts as "previous iteration"; init -INF
    // so the first fold is an identity (v_mov writes, no MFMA hazard).
    f32x16 cA0, cA1, cA2, cA3, cB0, cB1, cB2, cB3;
    #pragma unroll
    for (int r = 0; r < 16; ++r) {
        cB0[r] = -INFINITY; cB1[r] = -INFINITY;
        cB2[r] = -INFINITY; cB3[r] = -INFINITY;
    }

    // Staging buffers (2 x 16 KiB) alias the epilogue transpose buffer.
    __shared__ __align__(16) unsigned char smem[WAVES * 64 * 36 * 4];  // 36864 B

    // Each wave stages its 4 KiB slice: 4 x global_load_lds of 1 KiB
    // (64 lanes x 16B, linear dest = wave-uniform base + lane*16).
    const unsigned char* gsrc = Rb + (size_t)wave * 4096 + (size_t)lane * 16;
    unsigned char* lbase = smem + wave * 4096;
    auto stage_issue = [&](int s) {
        const unsigned char* g = gsrc + (size_t)s * STAGE_BYTES;
        unsigned char* l = lbase + ((s & 1) * STAGE_BYTES);
        #pragma unroll
        for (int k2 = 0; k2 < 4; ++k2)
            gload_lds16(g + k2 * 1024, l + k2 * 1024);
    };

    const int nStages = chunk / SREF;               // 8
    stage_issue(0);
    __syncthreads();                                // drains vmcnt(0)

    #pragma unroll 1
    for (int s = 0; s < nStages; ++s) {
        if (s + 1 < nStages) stage_issue(s + 1);    // fills other buffer
        // Lane l's pre-expanded 16B fragment of tiles 2i, 2i+1 at
        // tb + i*2048 (+1024). One-iteration register prefetch; the set
        // folded each half was issued the PREVIOUS half (pinned age >=
        // other-set fold ~64cyc + fence 8cyc).
        const unsigned char* tb = smem + ((s & 1) * STAGE_BYTES) + lane * 16;
        short8 b0 = *(const short8*)(tb);
        short8 b1 = *(const short8*)(tb + 1024);
        #pragma unroll
        for (int ii = 0; ii < IPS / 2; ++ii) {
            // half A: consume (b0,b1), prefetch odd-iter operands
            const short8 n0 = *(const short8*)(tb + (2 * ii + 1) * 2048);
            const short8 n1 = *(const short8*)(tb + (2 * ii + 1) * 2048 + 1024);
            cA0 = mfma_bf16_z(A0, b0);
            cA1 = mfma_bf16_z(A0, b1);
            cA2 = mfma_bf16_z(A1, b0);
            cA3 = mfma_bf16_z(A1, b1);
            SB();                                   // pin: nothing crosses
            mfma_fence4(cB0, cB1, cB2, cB3);
            fold4(cB0, cB1, cB2, cB3, k0, k1);      // prev iter's tuples

            // half B: consume (n0,n1), prefetch next even-iter operands
            short8 m0 = b0, m1 = b1;
            if (2 * ii + 2 < IPS) {
                m0 = *(const short8*)(tb + (2 * ii + 2) * 2048);
                m1 = *(const short8*)(tb + (2 * ii + 2) * 2048 + 1024);
            }
            cB0 = mfma_bf16_z(A0, n0);
            cB1 = mfma_bf16_z(A0, n1);
            cB2 = mfma_bf16_z(A1, n0);
            cB3 = mfma_bf16_z(A1, n1);
            SB();
            mfma_fence4(cA0, cA1, cA2, cA3);
            fold4(cA0, cA1, cA2, cA3, k0, k1);

            b0 = m0; b1 = m1;
        }
        __syncthreads();   // drains vmcnt(0): next buffer published
    }
    // Pipeline drain: last issued set is cB (final half-B).
    mfma_fence4(cB0, cB1, cB2, cB3);
    fold4(cB0, cB1, cB2, cB3, k0, k1);

    // ---- epilogue: LDS transpose, then each lane max-reduces one query row.
    // C/D layout: col=lane&31, row=(r&3)+8*(r>>2)+4*(lane>>5).
    float (*sT)[64][36] = (float (*)[64][36])smem;  // +4 pad: conflict-free
    #pragma unroll
    for (int r = 0; r < 16; ++r) {
        const int row = (r & 3) + 8 * (r >> 2) + 4 * (lane >> 5);
        sT[wave][row][m]      = k0[r];              // group 0 -> rows 0..31
        sT[wave][32 + row][m] = k1[r];              // group 1 -> rows 32..63
    }
    // wave-private region; compiler inserts the lgkmcnt waits.
    const float4* rowp = (const float4*)&sT[wave][lane][0];
    float4 m01 = rowp[0];
    #pragma unroll
    for (int kk = 1; kk < 8; ++kk) {
        const float4 t = rowp[kk];
        m01.x = fmaxf(m01.x, t.x); m01.y = fmaxf(m01.y, t.y);
        m01.z = fmaxf(m01.z, t.z); m01.w = fmaxf(m01.w, t.w);
    }
    const float cmax = fmaxf(fmaxf(m01.x, m01.y), fmaxf(m01.z, m01.w));
    outK[qBase + lane] = cmax;                      // coalesced, no atomics
}

// d2 = max(0, ||q||^2 - 2*max(kpart[0], kpart[1])); weighted means, one
// atomicAdd per block. q2 precomputed fp32 in prep.
__global__ void __launch_bounds__(BLOCK)
reduce_kernel(const float* __restrict__ kpart, const float* __restrict__ q2,
              int nG, int nP, float invx, float invy, float* __restrict__ out) {
    const int total = nG + nP;
    float local = 0.0f;
    for (int idx = blockIdx.x * blockDim.x + threadIdx.x; idx < total;
         idx += gridDim.x * blockDim.x) {
        const float c = fmaxf(kpart[idx], kpart[total + idx]);
        const float inv = (idx < nG) ? invx : invy;
        local += fmaxf(q2[idx] - 2.0f * c, 0.0f) * inv;
    }
    __shared__ float waveSums[BLOCK / 64];
    float v = local;
    #pragma unroll
    for (int off = 32; off; off >>= 1) v += __shfl_xor(v, off);
    if ((threadIdx.x & 63) == 0) waveSums[threadIdx.x >> 6] = v;
    __syncthreads();
    if (threadIdx.x == 0) {
        float s = 0.0f;
        #pragma unroll
        for (int w = 0; w < BLOCK / 64; ++w) s += waveSums[w];
        atomicAdd(out, s);
    }
}

extern "C" void kernel_launch(void* const* d_in, const int* in_sizes, int n_in,
                              void* d_out, int out_size, void* d_ws, size_t ws_size,
                              hipStream_t stream) {
    const float* gts   = (const float*)d_in[0];   // [B, N, 3]
    const float* preds = (const float*)d_in[1];   // [B, M, 3]
    float* out = (float*)d_out;

    const int B = 8;
    const int N = in_sizes[0] / (B * 3);
    const int M = in_sizes[1] / (B * 3);
    const int nG = B * N, nP = B * M;

    uint4* recQ = (uint4*)d_ws;                                // (nG+nP)*16B (2 MB)
    unsigned char* recB = (unsigned char*)(recQ + nG + nP);    // (nG+nP)*32B (4 MB)
    float* kpart = (float*)(recB + (size_t)(nG + nP) * 32);    // NCHUNK*(nG+nP) (1 MB)
    float* q2    = kpart + (size_t)NCHUNK * (nG + nP);         // (nG+nP) (0.5 MB)

    prep_kernel<<<(nG + nP + BLOCK - 1) / BLOCK, BLOCK, 0, stream>>>(
        gts, preds, nG, nP, recQ, recB, q2, out);

    dim3 grid(N / (WAVES * QPW), NCHUNK, 2 * B);  // 32 x 2 x 16 = 1024 blocks
    nn_kernel<<<grid, BLOCK, 0, stream>>>(recQ, recB, kpart, N, M, B);

    reduce_kernel<<<256, BLOCK, 0, stream>>>(
        kpart, q2, nG, nP, 1.0f / (float)nG, 1.0f / (float)nP, out);
}

// Round 5
// 98.116 us; speedup vs baseline: 1.0140x; 1.0005x over previous
//
#include <hip/hip_runtime.h>
#include <hip/hip_bf16.h>
#include <math.h>

// Chamfer distance via K-packed MFMA, B=8, N=M=8192, D=3, fp32.
//   C[m][n] = q_m.r_n - 0.5*||r_n||^2 via ONE v_mfma_f32_32x32x16_bf16:
//     lanes<32  (k0-7) : A={qh,1, ql,0}  B={rh,wh, rh,wh}
//     lanes>=32 (k8-15): A={qh,1, 0,0}   B={rl,wl, 0,0}
//   (hi/lo bf16 split; dropped ql.rl term ~2^-17 relative)
//   min_j d2 = ||q||^2_fp32 - 2*max_n C, clamped at 0.
// R11: R0/R8/R10 = three different schedules, SAME 42us -> the invariant is
// the asm-volatile MFMA wrapper. R0 counters: ~90 VALU/iter vs ~46 in source
// (VALUBusy 45.5% @ 2 waves/SIMD); the "=&v" 16-wide earlyclobber tuples
// under a 128-reg budget forced accvgpr_read/write shuffles + copy-outs
// around every fold - junk that scaled with MFMA count and survived all my
// schedule surgery. Fix: compiler intrinsic (m119 hit 99.8% of MFMA peak
// from intrinsics), NO hand scheduling, 256-reg budget (launch_bounds 256,2)
// so allocation stays pure-VGPR. Everything else (LDS staging via
// global_load_lds, pre-expanded B-fragments, LDS-transpose epilogue) kept.
// Predicted: nn 42 -> 15-20us (MfmaUtil 60-85), total ~73-78us.
// Pre-committed: if nn ~42 again, kernel body is exonerated; attack
// geometry/dispatch next.

#define BLOCK 256
#define WAVES 4
#define QPW 64        // queries per wave (two 32-row MFMA groups)
#define NCHUNK 2      // ref-dim split across blockIdx.y
#define SREF 512      // refs per LDS stage
#define STAGE_BYTES (SREF * 32)   // 16 KiB per buffer (32B per ref)
#define IPS (SREF / 64)           // 8 iterations per stage

typedef short short8 __attribute__((ext_vector_type(8)));
typedef float f32x16 __attribute__((ext_vector_type(16)));
typedef unsigned int u32;
typedef __attribute__((address_space(1))) const u32 gu32;
typedef __attribute__((address_space(3))) u32 lu32;

__device__ __forceinline__ unsigned int bf16hi(float f) {
    __hip_bfloat16 h = __float2bfloat16(f);
    return (unsigned int)*reinterpret_cast<unsigned short*>(&h);
}
__device__ __forceinline__ float bf16f(unsigned int u) {
    unsigned short us = (unsigned short)u;
    __hip_bfloat16 h;
    *reinterpret_cast<unsigned short*>(&h) = us;
    return __bfloat162float(h);
}

#define MFMA(a, b, c) __builtin_amdgcn_mfma_f32_32x32x16_bf16((a), (b), (c), 0, 0, 0)

__device__ __forceinline__ void gload_lds16(const void* g, void* l) {
    __builtin_amdgcn_global_load_lds((gu32*)g, (lu32*)l, 16, 0, 0);
}

// Per point:
//   recQ: one 16B record {xh|yh, zh|wh, xl|yl, zl|wl}, w = -0.5*||p||^2
//   recB: pre-expanded B-fragment stream, tile t = points [32t,32t+32),
//         1024B per tile:
//           bytes [t*1024 + m*16]       = {hx,hz, hx,hz}  (hi dup, lanes<32)
//           bytes [t*1024 + 512 + m*16] = {lx,lz, 0, 0}   (lo,     lanes>=32)
//   q2:   fp32 ||p||^2 (exact) for the reduce pass.
__global__ void prep_kernel(const float* __restrict__ gts, const float* __restrict__ preds,
                            int nG, int nP, uint4* __restrict__ recQ,
                            unsigned char* __restrict__ recB, float* __restrict__ q2,
                            float* out) {
    const int idx = blockIdx.x * blockDim.x + threadIdx.x;
    if (idx == 0) out[0] = 0.0f;
    if (idx >= nG + nP) return;
    const float* src;
    unsigned char* rb;
    if (idx < nG) {
        src = gts + 3 * (size_t)idx;
        rb  = recB + (size_t)(idx >> 5) * 1024 + (size_t)(idx & 31) * 16;
    } else {
        const int j = idx - nG;
        src = preds + 3 * (size_t)j;
        rb  = recB + (size_t)nG * 32 + (size_t)(j >> 5) * 1024 + (size_t)(j & 31) * 16;
    }
    const float x = src[0], y = src[1], z = src[2];
    const float n2 = x * x + y * y + z * z;
    const float w = -0.5f * n2;
    q2[idx] = n2;
    const unsigned int xh = bf16hi(x), yh = bf16hi(y), zh = bf16hi(z), wh = bf16hi(w);
    const unsigned int xl = bf16hi(x - bf16f(xh));
    const unsigned int yl = bf16hi(y - bf16f(yh));
    const unsigned int zl = bf16hi(z - bf16f(zh));
    const unsigned int wl = bf16hi(w - bf16f(wh));
    const unsigned int hx = xh | (yh << 16), hz = zh | (wh << 16);
    const unsigned int lx = xl | (yl << 16), lz = zl | (wl << 16);
    recQ[idx] = make_uint4(hx, hz, lx, lz);
    *(uint4*)(rb)       = make_uint4(hx, hz, hx, hz);
    *(uint4*)(rb + 512) = make_uint4(lx, lz, 0u, 0u);
}

// kpart layout: float kpart[NCHUNK][nG + nP]; slot = blockIdx.y.
__global__ void __launch_bounds__(BLOCK, 2)
nn_kernel(const uint4* __restrict__ recQ, const unsigned char* __restrict__ recB,
          float* __restrict__ kpart, int N, int M, int B) {
    const int z = blockIdx.z;
    const bool dirX = (z < B);
    const int b = dirX ? z : z - B;
    const int NQ = dirX ? N : M;
    const int NR = dirX ? M : N;
    const uint4* Qr = recQ + (dirX ? 0 : (size_t)B * N) + (size_t)b * NQ;
    const int chunk = NR / NCHUNK;
    const unsigned char* Rb = recB + (dirX ? (size_t)B * N * 32 : 0)
                              + ((size_t)b * NR + (size_t)blockIdx.y * chunk) * 32;
    const int nGP = B * (N + M);
    float* outK = kpart + (size_t)blockIdx.y * nGP + (dirX ? 0 : B * N) + (size_t)b * NQ;

    const int tid = threadIdx.x;
    const int lane = tid & 63;
    const int wave = tid >> 6;
    const int m = lane & 31;
    const unsigned int loMask = (lane >= 32) ? 0u : 0xFFFFFFFFu;
    const int qBase = (blockIdx.x * WAVES + wave) * QPW;

    // ---- A fragments (two 32-row groups)
    const uint4 q0 = Qr[qBase + m];
    const uint4 q1 = Qr[qBase + 32 + m];
    union { uint4 v; short8 s; } a;
    a.v.x = q0.x;                                   // (qxh, qyh)
    a.v.y = (q0.y & 0xFFFFu) | 0x3F800000u;         // (qzh, 1.0bf16)
    a.v.z = q0.z & loMask;                          // (qxl, qyl) | 0
    a.v.w = q0.w & 0xFFFFu & loMask;                // (qzl, 0)   | 0
    const short8 A0 = a.s;
    a.v.x = q1.x;
    a.v.y = (q1.y & 0xFFFFu) | 0x3F800000u;
    a.v.z = q1.z & loMask;
    a.v.w = q1.w & 0xFFFFu & loMask;
    const short8 A1 = a.s;

    f32x16 k0, k1, zc;
    #pragma unroll
    for (int r = 0; r < 16; ++r) { k0[r] = -INFINITY; k1[r] = -INFINITY; zc[r] = 0.0f; }

    // Staging buffers (2 x 16 KiB) alias the epilogue transpose buffer.
    __shared__ __align__(16) unsigned char smem[WAVES * 64 * 36 * 4];  // 36864 B

    // Each wave stages its 4 KiB slice: 4 x global_load_lds of 1 KiB
    // (64 lanes x 16B, linear dest = wave-uniform base + lane*16).
    const unsigned char* gsrc = Rb + (size_t)wave * 4096 + (size_t)lane * 16;
    unsigned char* lbase = smem + wave * 4096;
    auto stage_issue = [&](int s) {
        const unsigned char* g = gsrc + (size_t)s * STAGE_BYTES;
        unsigned char* l = lbase + ((s & 1) * STAGE_BYTES);
        #pragma unroll
        for (int k2 = 0; k2 < 4; ++k2)
            gload_lds16(g + k2 * 1024, l + k2 * 1024);
    };

    const int nStages = chunk / SREF;               // 8
    stage_issue(0);
    __syncthreads();                                // drains vmcnt(0)

    #pragma unroll 1
    for (int s = 0; s < nStages; ++s) {
        if (s + 1 < nStages) stage_issue(s + 1);    // fills other buffer
        // Lane l's pre-expanded 16B fragment of tiles 2i, 2i+1. No manual
        // pipelining: intrinsics let the compiler's hazard recognizer and
        // scheduler interleave ds_read / MFMA / max3 (m119-style codegen).
        const unsigned char* tb = smem + ((s & 1) * STAGE_BYTES) + lane * 16;
        #pragma unroll
        for (int i = 0; i < IPS; ++i) {
            const short8 b0 = *(const short8*)(tb + i * 2048);
            const short8 b1 = *(const short8*)(tb + i * 2048 + 1024);
            const f32x16 c0 = MFMA(A0, b0, zc);
            const f32x16 c1 = MFMA(A0, b1, zc);
            const f32x16 c2 = MFMA(A1, b0, zc);
            const f32x16 c3 = MFMA(A1, b1, zc);
            #pragma unroll
            for (int r = 0; r < 16; ++r)
                k0[r] = fmaxf(fmaxf(c0[r], c1[r]), k0[r]);   // v_max3
            #pragma unroll
            for (int r = 0; r < 16; ++r)
                k1[r] = fmaxf(fmaxf(c2[r], c3[r]), k1[r]);
        }
        __syncthreads();   // drains vmcnt(0): next buffer published
    }

    // ---- epilogue: LDS transpose, then each lane max-reduces one query row.
    // C/D layout: col=lane&31, row=(r&3)+8*(r>>2)+4*(lane>>5).
    float (*sT)[64][36] = (float (*)[64][36])smem;  // +4 pad: conflict-free
    #pragma unroll
    for (int r = 0; r < 16; ++r) {
        const int row = (r & 3) + 8 * (r >> 2) + 4 * (lane >> 5);
        sT[wave][row][m]      = k0[r];              // group 0 -> rows 0..31
        sT[wave][32 + row][m] = k1[r];              // group 1 -> rows 32..63
    }
    // wave-private region; compiler inserts the lgkmcnt waits.
    const float4* rowp = (const float4*)&sT[wave][lane][0];
    float4 m01 = rowp[0];
    #pragma unroll
    for (int kk = 1; kk < 8; ++kk) {
        const float4 t = rowp[kk];
        m01.x = fmaxf(m01.x, t.x); m01.y = fmaxf(m01.y, t.y);
        m01.z = fmaxf(m01.z, t.z); m01.w = fmaxf(m01.w, t.w);
    }
    const float cmax = fmaxf(fmaxf(m01.x, m01.y), fmaxf(m01.z, m01.w));
    outK[qBase + lane] = cmax;                      // coalesced, no atomics
}

// d2 = max(0, ||q||^2 - 2*max(kpart[0], kpart[1])); weighted means, one
// atomicAdd per block. q2 precomputed fp32 in prep.
__global__ void __launch_bounds__(BLOCK)
reduce_kernel(const float* __restrict__ kpart, const float* __restrict__ q2,
              int nG, int nP, float invx, float invy, float* __restrict__ out) {
    const int total = nG + nP;
    float local = 0.0f;
    for (int idx = blockIdx.x * blockDim.x + threadIdx.x; idx < total;
         idx += gridDim.x * blockDim.x) {
        const float c = fmaxf(kpart[idx], kpart[total + idx]);
        const float inv = (idx < nG) ? invx : invy;
        local += fmaxf(q2[idx] - 2.0f * c, 0.0f) * inv;
    }
    __shared__ float waveSums[BLOCK / 64];
    float v = local;
    #pragma unroll
    for (int off = 32; off; off >>= 1) v += __shfl_xor(v, off);
    if ((threadIdx.x & 63) == 0) waveSums[threadIdx.x >> 6] = v;
    __syncthreads();
    if (threadIdx.x == 0) {
        float s = 0.0f;
        #pragma unroll
        for (int w = 0; w < BLOCK / 64; ++w) s += waveSums[w];
        atomicAdd(out, s);
    }
}

extern "C" void kernel_launch(void* const* d_in, const int* in_sizes, int n_in,
                              void* d_out, int out_size, void* d_ws, size_t ws_size,
                              hipStream_t stream) {
    const float* gts   = (const float*)d_in[0];   // [B, N, 3]
    const float* preds = (const float*)d_in[1];   // [B, M, 3]
    float* out = (float*)d_out;

    const int B = 8;
    const int N = in_sizes[0] / (B * 3);
    const int M = in_sizes[1] / (B * 3);
    const int nG = B * N, nP = B * M;

    uint4* recQ = (uint4*)d_ws;                                // (nG+nP)*16B (2 MB)
    unsigned char* recB = (unsigned char*)(recQ + nG + nP);    // (nG+nP)*32B (4 MB)
    float* kpart = (float*)(recB + (size_t)(nG + nP) * 32);    // NCHUNK*(nG+nP) (1 MB)
    float* q2    = kpart + (size_t)NCHUNK * (nG + nP);         // (nG+nP) (0.5 MB)

    prep_kernel<<<(nG + nP + BLOCK - 1) / BLOCK, BLOCK, 0, stream>>>(
        gts, preds, nG, nP, recQ, recB, q2, out);

    dim3 grid(N / (WAVES * QPW), NCHUNK, 2 * B);  // 32 x 2 x 16 = 1024 blocks
    nn_kernel<<<grid, BLOCK, 0, stream>>>(recQ, recB, kpart, N, M, B);

    reduce_kernel<<<256, BLOCK, 0, stream>>>(
        kpart, q2, nG, nP, 1.0f / (float)nG, 1.0f / (float)nP, out);
}